// Round 10
// baseline (230.439 us; speedup 1.0000x reference)
//
#include <hip/hip_runtime.h>

// Problem constants
#define B     4
#define LQ    4096
#define LK    5119
#define LKP   5120              // per-batch padded rows (160 chunks of 32)
#define D     512
#define CACHE 1024
#define MQ    (B * LQ)          // 16384 = 128*128
#define MKP   (B * LKP)         // 20480 = 160*128
#define NCH   160               // 32-row chunks per batch
#define TI    32                // query rows per window block

typedef float  f32x4  __attribute__((ext_vector_type(4)));
typedef __bf16 bf16x2 __attribute__((ext_vector_type(2)));
typedef __bf16 bf16x8 __attribute__((ext_vector_type(8)));

// async global->LDS, 16B per lane; lds base wave-uniform (HW adds lane*16)
__device__ __forceinline__ void async16(void* lds, const void* g)
{
    __builtin_amdgcn_global_load_lds(
        (__attribute__((address_space(1))) void*)(g),
        (__attribute__((address_space(3))) void*)(lds),
        16, 0, 0);
}

// ---------------------------------------------------------------------------
// Kernel 1 (prep): z in {0,1,2}: LayerNorm -> bf16.
// R6: back to the R2 oversubscribed-grid structure (prep is TLP/latency-
// bound: R3's 1024-block persistent version dropped occupancy 57->32% and
// regressed 51->59us).  Each half-wave now owns TWO rows (r and r+8) with
// both rows' loads issued back-to-back -> 8 dwordx4 in flight per lane
// before the first dependent reduce (2x the in-flight bytes of R2) while
// keeping 5120 blocks (20/CU) for wave-level oversubscription.
// z == 3: weight transpose f32->bf16 (unchanged).
// NOTE (R7 lesson): plain stores only — nt-stores bypass L3 and force the
// consumer GEMM to re-read everything from HBM.
// ---------------------------------------------------------------------------
__global__ __launch_bounds__(256) void prep_kernel(
    const float* __restrict__ q, const float* __restrict__ k,
    const float* __restrict__ v,
    const float* __restrict__ gq, const float* __restrict__ bq,
    const float* __restrict__ gk, const float* __restrict__ bk,
    const float* __restrict__ gv, const float* __restrict__ bv,
    const float* __restrict__ Wq, const float* __restrict__ Wk,
    const float* __restrict__ Wv,
    __bf16* __restrict__ qn, __bf16* __restrict__ kn, __bf16* __restrict__ vn,
    __bf16* __restrict__ wtq, __bf16* __restrict__ wtk, __bf16* __restrict__ wtv)
{
    const int z = blockIdx.y;

    if (z == 3) {               // ---- weight transpose-convert ----
        const int idx = blockIdx.x;
        if (idx >= 384) return;
        const int zz  = idx >> 7;        // 0..2
        const int rem = idx & 127;
        const float* W = (zz == 0) ? Wq : (zz == 1) ? Wk : Wv;
        __bf16*     Wt = (zz == 0) ? wtq : (zz == 1) ? wtk : wtv;
        const int n  = (rem & 1) * 256 + threadIdx.x;
        const int k0 = (rem >> 1) * 8;
        bf16x8 o;
#pragma unroll
        for (int j = 0; j < 8; ++j)
            o[j] = (__bf16)W[(long)(k0 + j) * D + n];
        *reinterpret_cast<bf16x8*>(Wt + (long)n * D + k0) = o;
        return;
    }

    // ---- LayerNorm: two rows per half-wave ----
    const float *x, *g, *bb; __bf16* o;
    if (z == 0)      { x = q; g = gq; bb = bq; o = qn; }
    else if (z == 1) { x = k; g = gk; bb = bk; o = kn; }
    else             { x = v; g = gv; bb = bv; o = vn; }

    const int nrows = (z == 0) ? MQ : MKP;
    const int rsub  = threadIdx.x >> 5;           // 0..7
    const int c0    = (threadIdx.x & 31) * 16;    // 16 floats per lane
    const int rp0   = blockIdx.x * 16 + rsub;     // first row
    const int rp1   = rp0 + 8;                    // second row
    if (rp0 >= nrows) return;                     // z==0 tail blocks

    // row source address (pad row clamped; store predicated off)
    auto rowaddr = [&](int rp, bool& valid) -> const float* {
        long rin; valid = true;
        if (z == 0) rin = rp;
        else {
            const int bch = rp / LKP;
            int i = rp - bch * LKP;
            if (i == LK) { valid = false; i = LK - 1; }  // pad row
            rin = (long)bch * LK + i;
        }
        return x + rin * D + c0;
    };

    bool vA, vB;
    const float* pA = rowaddr(rp0, vA);
    const float* pB = rowaddr(rp1, vB);

    // issue ALL loads for both rows before any dependent use (8 dwordx4)
    float4 a[4], bfr[4];
#pragma unroll
    for (int j = 0; j < 4; ++j)
        a[j]   = *reinterpret_cast<const float4*>(pA + j * 4);
#pragma unroll
    for (int j = 0; j < 4; ++j)
        bfr[j] = *reinterpret_cast<const float4*>(pB + j * 4);

    // hoisted gamma/beta (L1/L2-resident after first block)
    float4 gr[4], br[4];
#pragma unroll
    for (int j = 0; j < 4; ++j) {
        gr[j] = *reinterpret_cast<const float4*>(g  + c0 + j * 4);
        br[j] = *reinterpret_cast<const float4*>(bb + c0 + j * 4);
    }

    auto process = [&](const float4* r, int rp, bool valid) {
        float s = 0.f, ss = 0.f;
#pragma unroll
        for (int j = 0; j < 4; ++j) {
            s  += r[j].x + r[j].y + r[j].z + r[j].w;
            ss += r[j].x*r[j].x + r[j].y*r[j].y + r[j].z*r[j].z + r[j].w*r[j].w;
        }
#pragma unroll
        for (int m = 1; m <= 16; m <<= 1) {   // reduce within 32-lane half
            s  += __shfl_xor(s,  m, 64);
            ss += __shfl_xor(ss, m, 64);
        }
        const float mean = s * (1.f / (float)D);
        const float var  = ss * (1.f / (float)D) - mean * mean;
        const float rs   = rsqrtf(var + 1e-5f);

        bf16x8 o0, o1;
#pragma unroll
        for (int j = 0; j < 4; ++j) {
            const float y0 = (r[j].x - mean) * rs * gr[j].x + br[j].x;
            const float y1 = (r[j].y - mean) * rs * gr[j].y + br[j].y;
            const float y2 = (r[j].z - mean) * rs * gr[j].z + br[j].z;
            const float y3 = (r[j].w - mean) * rs * gr[j].w + br[j].w;
            if (j < 2) {
                o0[j*4+0] = (__bf16)y0; o0[j*4+1] = (__bf16)y1;
                o0[j*4+2] = (__bf16)y2; o0[j*4+3] = (__bf16)y3;
            } else {
                o1[(j-2)*4+0] = (__bf16)y0; o1[(j-2)*4+1] = (__bf16)y1;
                o1[(j-2)*4+2] = (__bf16)y2; o1[(j-2)*4+3] = (__bf16)y3;
            }
        }
        if (valid) {
            __bf16* orow = o + (long)rp * D + c0;
            *reinterpret_cast<bf16x8*>(orow)     = o0;
            *reinterpret_cast<bf16x8*>(orow + 8) = o1;
        }
    };

    process(a,   rp0, vA);
    process(bfr, rp1, vB);
}

// ---------------------------------------------------------------------------
// Kernel 2 (gemm_fused):
//   bid <  640 -> kv = relu(kn@Wk + bwk) * (vn@Wv + bwv) (128x128 tile) with
//                 fused 32-row chunk sums stored to Csum.
//   bid >= 640 -> qp = relu(qn@Wq + bwq) (128x128 tile).
// R2a (LPT): kv blocks (the ~2x-longer jobs) launch FIRST.
// R3 (q-path): LDS double-buffer, ONE barrier per K-step — stage(t+1) is
// issued at phase top into the idle buffer and covered by the whole step
// (frag reads + MFMA), not just the tail MFMA cluster.
// kv path: 2-barrier single-buffer (holding K+V frag sets simultaneously
// would exceed the VGPR budget); stage(t+1) covered by the V-MFMA cluster.
// Block order: mtile-INNER on both paths (XCD affinity: offsets ≡0 mod 8).
// BK=64, async16 staging, XOR-swizzled 16B chunks (conflict-free).
// ---------------------------------------------------------------------------
__global__ __launch_bounds__(256, 2) void gemm_fused_kernel(
    const __bf16* __restrict__ qn, const __bf16* __restrict__ kn,
    const __bf16* __restrict__ vn,
    const __bf16* __restrict__ wtq, const __bf16* __restrict__ wtk,
    const __bf16* __restrict__ wtv,
    const float* __restrict__ bwq, const float* __restrict__ bwk,
    const float* __restrict__ bwv,
    __bf16* __restrict__ qpb, __bf16* __restrict__ kvb,
    float* __restrict__ Csum)
{
    __shared__ __attribute__((aligned(16))) __bf16 smem[32768];  // 64 KB

    const int bid  = blockIdx.x;
    const int tid  = threadIdx.x;
    const int lane = tid & 63;
    const int wave = tid >> 6;
    const int quad = lane >> 4;
    const int l16  = lane & 15;
    const int wm   = wave >> 1;
    const int wn   = wave & 1;
    const int lrow = lane >> 3;                    // 0..7
    const int lcs  = ((lane & 7) ^ lrow) * 8;      // swizzled k-col (bf16)

    if (bid < 640) {
        // ================= kv dual GEMM: 128x128 tile =================
        __bf16* Ks  = smem;               // 128*64
        __bf16* Vs  = smem + 8192;        // 128*64
        __bf16* WKs = smem + 16384;       // 128*64
        __bf16* WVs = smem + 24576;       // 128*64

        const int ntile = bid / 160;      // 0..3 (mtile-inner, 160%8==0)
        const int mtile = bid - ntile * 160;

        f32x4 acck[4][4], accv[4][4];
#pragma unroll
        for (int i = 0; i < 4; ++i)
#pragma unroll
            for (int j = 0; j < 4; ++j) {
                acck[i][j] = (f32x4){0.f, 0.f, 0.f, 0.f};
                accv[i][j] = (f32x4){0.f, 0.f, 0.f, 0.f};
            }

        const long arow0 = (long)mtile * 128;
        const long brow0 = (long)ntile * 128;

        auto stage_kv = [&](int kk) {
#pragma unroll
            for (int j = 0; j < 4; ++j) {
                const int r0  = (j * 4 + wave) * 8;
                const int row = r0 + lrow;
                async16(&Ks [r0 * 64], &kn [(arow0 + row) * D + kk + lcs]);
                async16(&Vs [r0 * 64], &vn [(arow0 + row) * D + kk + lcs]);
                async16(&WKs[r0 * 64], &wtk[(brow0 + row) * D + kk + lcs]);
                async16(&WVs[r0 * 64], &wtv[(brow0 + row) * D + kk + lcs]);
            }
        };

        stage_kv(0);                       // prologue
        for (int kt = 0; kt < 8; ++kt) {
            __syncthreads();               // A: stage(kt) landed in LDS

            bf16x8 fa[4][2], fb[4][2];
            // ---- K-frags + K GEMM ----
#pragma unroll
            for (int tm = 0; tm < 4; ++tm) {
                const int m = wm * 64 + tm * 16 + l16;
#pragma unroll
                for (int kh = 0; kh < 2; ++kh)
                    fa[tm][kh] = *reinterpret_cast<const bf16x8*>(
                        &Ks[m * 64 + (((kh * 4 + quad) ^ (m & 7)) * 8)]);
            }
#pragma unroll
            for (int tn = 0; tn < 4; ++tn) {
                const int n = wn * 64 + tn * 16 + l16;
#pragma unroll
                for (int kh = 0; kh < 2; ++kh)
                    fb[tn][kh] = *reinterpret_cast<const bf16x8*>(
                        &WKs[n * 64 + (((kh * 4 + quad) ^ (n & 7)) * 8)]);
            }
#pragma unroll
            for (int kh = 0; kh < 2; ++kh)
#pragma unroll
                for (int tm = 0; tm < 4; ++tm)
#pragma unroll
                    for (int tn = 0; tn < 4; ++tn)
                        acck[tm][tn] = __builtin_amdgcn_mfma_f32_16x16x32_bf16(
                            fa[tm][kh], fb[tn][kh], acck[tm][tn], 0, 0, 0);
            // ---- V-frags into regs ----
#pragma unroll
            for (int tm = 0; tm < 4; ++tm) {
                const int m = wm * 64 + tm * 16 + l16;
#pragma unroll
                for (int kh = 0; kh < 2; ++kh)
                    fa[tm][kh] = *reinterpret_cast<const bf16x8*>(
                        &Vs[m * 64 + (((kh * 4 + quad) ^ (m & 7)) * 8)]);
            }
#pragma unroll
            for (int tn = 0; tn < 4; ++tn) {
                const int n = wn * 64 + tn * 16 + l16;
#pragma unroll
                for (int kh = 0; kh < 2; ++kh)
                    fb[tn][kh] = *reinterpret_cast<const bf16x8*>(
                        &WVs[n * 64 + (((kh * 4 + quad) ^ (n & 7)) * 8)]);
            }
            __syncthreads();               // B: every wave done reading LDS
            if (kt < 7) stage_kv((kt + 1) * 64);   // overlap with V-MFMA
            // ---- V GEMM (stage(kt+1) in flight) ----
#pragma unroll
            for (int kh = 0; kh < 2; ++kh)
#pragma unroll
                for (int tm = 0; tm < 4; ++tm)
#pragma unroll
                    for (int tn = 0; tn < 4; ++tn)
                        accv[tm][tn] = __builtin_amdgcn_mfma_f32_16x16x32_bf16(
                            fa[tm][kh], fb[tn][kh], accv[tm][tn], 0, 0, 0);
        }

        // epilogue: write kv (bf16) and accumulate 32-row chunk partials
        float part[4][2];
#pragma unroll
        for (int tn = 0; tn < 4; ++tn) { part[tn][0] = 0.f; part[tn][1] = 0.f; }
#pragma unroll
        for (int tm = 0; tm < 4; ++tm) {
            const long row0 = arow0 + wm * 64 + tm * 16 + quad * 4;
#pragma unroll
            for (int tn = 0; tn < 4; ++tn) {
                const int col = (int)brow0 + wn * 64 + tn * 16 + l16;
                const float bkc = bwk[col];
                const float bvc = bwv[col];
#pragma unroll
                for (int r = 0; r < 4; ++r) {
                    const float kp = fmaxf(acck[tm][tn][r] + bkc, 0.f);
                    const float vp = accv[tm][tn][r] + bvc;
                    const __bf16 kb = (__bf16)(kp * vp);
                    kvb[(row0 + r) * D + col] = kb;
                    part[tn][tm >> 1] += (float)kb;
                }
            }
        }
        // reduce over quads (rows within the 32-row chunk) and store Csum
#pragma unroll
        for (int tn = 0; tn < 4; ++tn)
#pragma unroll
            for (int th = 0; th < 2; ++th) {
                float vv = part[tn][th];
                vv += __shfl_xor(vv, 16, 64);
                vv += __shfl_xor(vv, 32, 64);
                if (quad == 0) {
                    const int fc = ((int)(arow0 >> 5)) + wm * 2 + th; // flat chunk
                    const int bb = fc / NCH;
                    const int cc = fc - bb * NCH;
                    const int col = (int)brow0 + wn * 64 + tn * 16 + l16;
                    Csum[((long)bb * NCH + cc) * D + col] = vv;
                }
            }
    } else {
        // ============ q GEMM: 128x128 tile, LDS double-buffered ============
        __bf16* Asb[2] = { smem,         smem + 16384 };   // 128*64 each
        __bf16* Bsb[2] = { smem + 8192,  smem + 24576 };

        const int bidq = bid - 640;

        f32x4 acc[4][4];
#pragma unroll
        for (int i = 0; i < 4; ++i)
#pragma unroll
            for (int j = 0; j < 4; ++j)
                acc[i][j] = (f32x4){0.f, 0.f, 0.f, 0.f};

        const long arow0 = (long)(bidq & 127) * 128;   // mtile-inner
        const long brow0 = (long)(bidq >> 7) * 128;    // 4 ntile passes

        auto stage_q = [&](int kk, int p) {
#pragma unroll
            for (int j = 0; j < 4; ++j) {
                const int r0  = (j * 4 + wave) * 8;
                const int row = r0 + lrow;
                async16(&Asb[p][r0 * 64], &qn [(arow0 + row) * D + kk + lcs]);
                async16(&Bsb[p][r0 * 64], &wtq[(brow0 + row) * D + kk + lcs]);
            }
        };

        stage_q(0, 0);                     // prologue
        __syncthreads();                   // buf0 ready
        for (int kt = 0; kt < 8; ++kt) {
            const int p = kt & 1;
            if (kt < 7) stage_q((kt + 1) * 64, p ^ 1);   // into idle buffer

            bf16x8 af[4][2], bf[4][2];
#pragma unroll
            for (int tm = 0; tm < 4; ++tm) {
                const int m = wm * 64 + tm * 16 + l16;
#pragma unroll
                for (int kh = 0; kh < 2; ++kh)
                    af[tm][kh] = *reinterpret_cast<const bf16x8*>(
                        &Asb[p][m * 64 + (((kh * 4 + quad) ^ (m & 7)) * 8)]);
            }
#pragma unroll
            for (int tn = 0; tn < 4; ++tn) {
                const int n = wn * 64 + tn * 16 + l16;
#pragma unroll
                for (int kh = 0; kh < 2; ++kh)
                    bf[tn][kh] = *reinterpret_cast<const bf16x8*>(
                        &Bsb[p][n * 64 + (((kh * 4 + quad) ^ (n & 7)) * 8)]);
            }
#pragma unroll
            for (int kh = 0; kh < 2; ++kh)
#pragma unroll
                for (int tm = 0; tm < 4; ++tm)
#pragma unroll
                    for (int tn = 0; tn < 4; ++tn)
                        acc[tm][tn] = __builtin_amdgcn_mfma_f32_16x16x32_bf16(
                            af[tm][kh], bf[tn][kh], acc[tm][tn], 0, 0, 0);
            // barrier: (1) drains stage(kt+1) [covered by reads+MFMA above],
            // (2) all waves done reading buf p before kt+1 restages it.
            if (kt < 7) __syncthreads();
        }

#pragma unroll
        for (int tm = 0; tm < 4; ++tm) {
            const long row0 = arow0 + wm * 64 + tm * 16 + quad * 4;
#pragma unroll
            for (int tn = 0; tn < 4; ++tn) {
                const int col = (int)brow0 + wn * 64 + tn * 16 + l16;
                const float bv = bwq[col];
#pragma unroll
                for (int r = 0; r < 4; ++r)
                    qpb[(row0 + r) * D + col] =
                        (__bf16)fmaxf(acc[tm][tn][r] + bv, 0.f);
            }
        }
    }
}

// ---------------------------------------------------------------------------
// Kernel 3: sliding window (1024) via chunk-sum init + rolling edges,
// times relu(qp).  TI=32 query rows/block, 2 cols/thread.
// ---------------------------------------------------------------------------
__global__ __launch_bounds__(256) void window_kernel(
    const __bf16* __restrict__ kv, const float* __restrict__ Csum,
    const __bf16* __restrict__ qpb, float* __restrict__ out)
{
    const int iq   = blockIdx.x;        // 0..127
    const int b    = blockIdx.y;
    const int i0   = iq * TI;
    const int col2 = threadIdx.x * 2;

    const float* cs = Csum + (long)b * NCH * D + col2;
    float s0 = 0.f, s1 = 0.f;
#pragma unroll
    for (int c = 0; c < 32; ++c) {
        const float2 cv = *reinterpret_cast<const float2*>(cs + (long)(iq + c) * D);
        s0 += cv.x; s1 += cv.y;
    }

    const __bf16* kvb = kv  + (long)b * LKP * D + col2;
    const __bf16* qb  = qpb + (long)b * LQ  * D + col2;
    float*        ob  = out + (long)b * LQ  * D + col2;

#pragma unroll 8
    for (int i = i0; i < i0 + TI; ++i) {
        const bf16x2 qv = *reinterpret_cast<const bf16x2*>(qb + (long)i * D);
        *reinterpret_cast<float2*>(ob + (long)i * D) =
            make_float2((float)qv[0] * s0, (float)qv[1] * s1);
        const bf16x2 lead  = *reinterpret_cast<const bf16x2*>(kvb + (long)(i + CACHE) * D);
        const bf16x2 trail = *reinterpret_cast<const bf16x2*>(kvb + (long)i * D);
        s0 += (float)lead[0] - (float)trail[0];
        s1 += (float)lead[1] - (float)trail[1];
    }
}

// ---------------------------------------------------------------------------
extern "C" void kernel_launch(void* const* d_in, const int* in_sizes, int n_in,
                              void* d_out, int out_size, void* d_ws, size_t ws_size,
                              hipStream_t stream)
{
    const float* q   = (const float*)d_in[0];
    const float* k   = (const float*)d_in[1];
    const float* v   = (const float*)d_in[2];
    const float* gq  = (const float*)d_in[3];
    const float* bq  = (const float*)d_in[4];
    const float* gk  = (const float*)d_in[5];
    const float* bk  = (const float*)d_in[6];
    const float* gv  = (const float*)d_in[7];
    const float* bv  = (const float*)d_in[8];
    const float* Wq  = (const float*)d_in[9];
    const float* bwq = (const float*)d_in[10];
    const float* Wk  = (const float*)d_in[11];
    const float* bwk = (const float*)d_in[12];
    const float* Wv  = (const float*)d_in[13];
    const float* bwv = (const float*)d_in[14];
    float* out = (float*)d_out;

    // Workspace layout (k/v-side tensors per-batch padded: stride LKP rows)
    char* ws = (char*)d_ws;
    __bf16* qn   = (__bf16*)ws;                      // [MQ ][D] bf16
    __bf16* kn   = qn  + (long)MQ  * D;              // [MKP][D] bf16 (padded)
    __bf16* vn   = kn  + (long)MKP * D;              // [MKP][D] bf16 (padded)
    __bf16* qpb  = vn  + (long)MKP * D;              // [MQ ][D] bf16  relu(qp)
    __bf16* kvb  = qpb + (long)MQ  * D;              // [MKP][D] bf16 (padded)
    __bf16* wtq  = kvb + (long)MKP * D;              // [D][D] bf16 transposed
    __bf16* wtk  = wtq + (long)D * D;
    __bf16* wtv  = wtk + (long)D * D;
    float*  Csum = (float*)(wtv + (long)D * D);      // [B][NCH][D] f32

    // 1) LN(q,k,v) + weight transpose in ONE dispatch
    //    (2 rows per half-wave: z=0 uses 1024 blocks, z=1/2 use 1280)
    prep_kernel<<<dim3(1280, 4), 256, 0, stream>>>(
        q, k, v, gq, bq, gk, bk, gv, bv, Wq, Wk, Wv,
        qn, kn, vn, wtq, wtk, wtv);

    // 2) kv-dual-GEMM (640 blocks, FIRST: LPT) + qp-GEMM (512 blocks)
    gemm_fused_kernel<<<640 + 512, 256, 0, stream>>>(
        qn, kn, vn, wtq, wtk, wtv, bwq, bwk, bwv, qpb, kvb, Csum);

    // 3) window sum x relu(qp)
    window_kernel<<<dim3(LQ / TI, B), 256, 0, stream>>>(kvb, Csum, qpb, out);
}

// Round 11
// 227.727 us; speedup vs baseline: 1.0119x; 1.0119x over previous
//
#include <hip/hip_runtime.h>

// Problem constants
#define B     4
#define LQ    4096
#define LK    5119
#define LKP   5120              // per-batch padded rows (160 chunks of 32)
#define D     512
#define CACHE 1024
#define MQ    (B * LQ)          // 16384 = 128*128
#define MKP   (B * LKP)         // 20480 = 160*128
#define NCH   160               // 32-row chunks per batch
#define TI    32                // query rows per window block

typedef float  f32x4  __attribute__((ext_vector_type(4)));
typedef __bf16 bf16x2 __attribute__((ext_vector_type(2)));
typedef __bf16 bf16x4 __attribute__((ext_vector_type(4)));
typedef __bf16 bf16x8 __attribute__((ext_vector_type(8)));

// async global->LDS, 16B per lane; lds base wave-uniform (HW adds lane*16)
__device__ __forceinline__ void async16(void* lds, const void* g)
{
    __builtin_amdgcn_global_load_lds(
        (__attribute__((address_space(1))) void*)(g),
        (__attribute__((address_space(3))) void*)(lds),
        16, 0, 0);
}

// ---------------------------------------------------------------------------
// Kernel 1 (prep): z in {0,1,2}: LayerNorm -> bf16.
// R10: ONE WAVE PER ROW with instruction-contiguous access.  R2/R3/R6 all
// gave lane i a 64B chunk (per-instruction lane stride 64B -> each dwordx4
// touches 32 scattered cachelines, 25% line use per instruction) and all
// three saturated at 2.1-2.4 TB/s despite different TLP/MLP mixes.  Now
// lane i loads row[i*4] and row[256+i*4]: two dwordx4, each a perfectly
// contiguous 1KB wave footprint (the m13 6.3TB/s pattern).  Stores are two
// contiguous 512B bf16x4 instructions.  6-step full-wave butterfly reduce.
// z == 3: weight transpose f32->bf16 (unchanged).
// NOTE (R7 lesson): plain stores only — nt-stores bypass L3 and force the
// consumer GEMM to re-read everything from HBM.
// ---------------------------------------------------------------------------
__global__ __launch_bounds__(256) void prep_kernel(
    const float* __restrict__ q, const float* __restrict__ k,
    const float* __restrict__ v,
    const float* __restrict__ gq, const float* __restrict__ bq,
    const float* __restrict__ gk, const float* __restrict__ bk,
    const float* __restrict__ gv, const float* __restrict__ bv,
    const float* __restrict__ Wq, const float* __restrict__ Wk,
    const float* __restrict__ Wv,
    __bf16* __restrict__ qn, __bf16* __restrict__ kn, __bf16* __restrict__ vn,
    __bf16* __restrict__ wtq, __bf16* __restrict__ wtk, __bf16* __restrict__ wtv)
{
    const int z = blockIdx.y;

    if (z == 3) {               // ---- weight transpose-convert ----
        const int idx = blockIdx.x;
        if (idx >= 384) return;
        const int zz  = idx >> 7;        // 0..2
        const int rem = idx & 127;
        const float* W = (zz == 0) ? Wq : (zz == 1) ? Wk : Wv;
        __bf16*     Wt = (zz == 0) ? wtq : (zz == 1) ? wtk : wtv;
        const int n  = (rem & 1) * 256 + threadIdx.x;
        const int k0 = (rem >> 1) * 8;
        bf16x8 o;
#pragma unroll
        for (int j = 0; j < 8; ++j)
            o[j] = (__bf16)W[(long)(k0 + j) * D + n];
        *reinterpret_cast<bf16x8*>(Wt + (long)n * D + k0) = o;
        return;
    }

    // ---- LayerNorm: one wave per row, instruction-contiguous ----
    const float *x, *g, *bb; __bf16* o;
    if (z == 0)      { x = q; g = gq; bb = bq; o = qn; }
    else if (z == 1) { x = k; g = gk; bb = bk; o = kn; }
    else             { x = v; g = gv; bb = bv; o = vn; }

    const int nrows = (z == 0) ? MQ : MKP;
    const int wid   = threadIdx.x >> 6;          // 0..3: wave in block
    const int lane  = threadIdx.x & 63;
    const int rp    = blockIdx.x * 4 + wid;      // padded row id
    if (rp >= nrows) return;                     // z==0 tail blocks

    long rin; bool valid = true;
    if (z == 0) rin = rp;
    else {
        const int bch = rp / LKP;
        int i = rp - bch * LKP;
        if (i == LK) { valid = false; i = LK - 1; }  // pad row: dummy load
        rin = (long)bch * LK + i;
    }

    const int    c0 = lane * 4;                  // 16B chunk within half-row
    const float* xr = x + rin * D;

    // two loads, each a contiguous 1KB wave footprint
    const float4 a0 = *reinterpret_cast<const float4*>(xr + c0);
    const float4 a1 = *reinterpret_cast<const float4*>(xr + 256 + c0);

    float s  = a0.x + a0.y + a0.z + a0.w + a1.x + a1.y + a1.z + a1.w;
    float ss = a0.x*a0.x + a0.y*a0.y + a0.z*a0.z + a0.w*a0.w
             + a1.x*a1.x + a1.y*a1.y + a1.z*a1.z + a1.w*a1.w;
#pragma unroll
    for (int m = 1; m <= 32; m <<= 1) {          // full 64-lane butterfly
        s  += __shfl_xor(s,  m, 64);
        ss += __shfl_xor(ss, m, 64);
    }
    const float mean = s * (1.f / (float)D);
    const float var  = ss * (1.f / (float)D) - mean * mean;
    const float rs   = rsqrtf(var + 1e-5f);

    const float4 g0 = *reinterpret_cast<const float4*>(g  + c0);
    const float4 g1 = *reinterpret_cast<const float4*>(g  + 256 + c0);
    const float4 b0 = *reinterpret_cast<const float4*>(bb + c0);
    const float4 b1 = *reinterpret_cast<const float4*>(bb + 256 + c0);

    bf16x4 o0, o1;
    o0[0] = (__bf16)((a0.x - mean) * rs * g0.x + b0.x);
    o0[1] = (__bf16)((a0.y - mean) * rs * g0.y + b0.y);
    o0[2] = (__bf16)((a0.z - mean) * rs * g0.z + b0.z);
    o0[3] = (__bf16)((a0.w - mean) * rs * g0.w + b0.w);
    o1[0] = (__bf16)((a1.x - mean) * rs * g1.x + b1.x);
    o1[1] = (__bf16)((a1.y - mean) * rs * g1.y + b1.y);
    o1[2] = (__bf16)((a1.z - mean) * rs * g1.z + b1.z);
    o1[3] = (__bf16)((a1.w - mean) * rs * g1.w + b1.w);

    if (valid) {
        __bf16* orow = o + (long)rp * D;
        *reinterpret_cast<bf16x4*>(orow + c0)       = o0;   // contiguous 512B
        *reinterpret_cast<bf16x4*>(orow + 256 + c0) = o1;   // contiguous 512B
    }
}

// ---------------------------------------------------------------------------
// Kernel 2 (gemm_fused):
//   bid <  640 -> kv = relu(kn@Wk + bwk) * (vn@Wv + bwv) (128x128 tile) with
//                 fused 32-row chunk sums stored to Csum.
//   bid >= 640 -> qp = relu(qn@Wq + bwq) (128x128 tile).
// R2a (LPT): kv blocks (the ~2x-longer jobs) launch FIRST.
// R3 (q-path): LDS double-buffer, ONE barrier per K-step — stage(t+1) is
// issued at phase top into the idle buffer and covered by the whole step
// (frag reads + MFMA), not just the tail MFMA cluster.
// kv path: 2-barrier single-buffer (holding K+V frag sets simultaneously
// would exceed the VGPR budget); stage(t+1) covered by the V-MFMA cluster.
// Block order: mtile-INNER on both paths (XCD affinity: offsets ≡0 mod 8).
// BK=64, async16 staging, XOR-swizzled 16B chunks (conflict-free).
// ---------------------------------------------------------------------------
__global__ __launch_bounds__(256, 2) void gemm_fused_kernel(
    const __bf16* __restrict__ qn, const __bf16* __restrict__ kn,
    const __bf16* __restrict__ vn,
    const __bf16* __restrict__ wtq, const __bf16* __restrict__ wtk,
    const __bf16* __restrict__ wtv,
    const float* __restrict__ bwq, const float* __restrict__ bwk,
    const float* __restrict__ bwv,
    __bf16* __restrict__ qpb, __bf16* __restrict__ kvb,
    float* __restrict__ Csum)
{
    __shared__ __attribute__((aligned(16))) __bf16 smem[32768];  // 64 KB

    const int bid  = blockIdx.x;
    const int tid  = threadIdx.x;
    const int lane = tid & 63;
    const int wave = tid >> 6;
    const int quad = lane >> 4;
    const int l16  = lane & 15;
    const int wm   = wave >> 1;
    const int wn   = wave & 1;
    const int lrow = lane >> 3;                    // 0..7
    const int lcs  = ((lane & 7) ^ lrow) * 8;      // swizzled k-col (bf16)

    if (bid < 640) {
        // ================= kv dual GEMM: 128x128 tile =================
        __bf16* Ks  = smem;               // 128*64
        __bf16* Vs  = smem + 8192;        // 128*64
        __bf16* WKs = smem + 16384;       // 128*64
        __bf16* WVs = smem + 24576;       // 128*64

        const int ntile = bid / 160;      // 0..3 (mtile-inner, 160%8==0)
        const int mtile = bid - ntile * 160;

        f32x4 acck[4][4], accv[4][4];
#pragma unroll
        for (int i = 0; i < 4; ++i)
#pragma unroll
            for (int j = 0; j < 4; ++j) {
                acck[i][j] = (f32x4){0.f, 0.f, 0.f, 0.f};
                accv[i][j] = (f32x4){0.f, 0.f, 0.f, 0.f};
            }

        const long arow0 = (long)mtile * 128;
        const long brow0 = (long)ntile * 128;

        auto stage_kv = [&](int kk) {
#pragma unroll
            for (int j = 0; j < 4; ++j) {
                const int r0  = (j * 4 + wave) * 8;
                const int row = r0 + lrow;
                async16(&Ks [r0 * 64], &kn [(arow0 + row) * D + kk + lcs]);
                async16(&Vs [r0 * 64], &vn [(arow0 + row) * D + kk + lcs]);
                async16(&WKs[r0 * 64], &wtk[(brow0 + row) * D + kk + lcs]);
                async16(&WVs[r0 * 64], &wtv[(brow0 + row) * D + kk + lcs]);
            }
        };

        stage_kv(0);                       // prologue
        for (int kt = 0; kt < 8; ++kt) {
            __syncthreads();               // A: stage(kt) landed in LDS

            bf16x8 fa[4][2], fb[4][2];
            // ---- K-frags + K GEMM ----
#pragma unroll
            for (int tm = 0; tm < 4; ++tm) {
                const int m = wm * 64 + tm * 16 + l16;
#pragma unroll
                for (int kh = 0; kh < 2; ++kh)
                    fa[tm][kh] = *reinterpret_cast<const bf16x8*>(
                        &Ks[m * 64 + (((kh * 4 + quad) ^ (m & 7)) * 8)]);
            }
#pragma unroll
            for (int tn = 0; tn < 4; ++tn) {
                const int n = wn * 64 + tn * 16 + l16;
#pragma unroll
                for (int kh = 0; kh < 2; ++kh)
                    fb[tn][kh] = *reinterpret_cast<const bf16x8*>(
                        &WKs[n * 64 + (((kh * 4 + quad) ^ (n & 7)) * 8)]);
            }
#pragma unroll
            for (int kh = 0; kh < 2; ++kh)
#pragma unroll
                for (int tm = 0; tm < 4; ++tm)
#pragma unroll
                    for (int tn = 0; tn < 4; ++tn)
                        acck[tm][tn] = __builtin_amdgcn_mfma_f32_16x16x32_bf16(
                            fa[tm][kh], fb[tn][kh], acck[tm][tn], 0, 0, 0);
            // ---- V-frags into regs ----
#pragma unroll
            for (int tm = 0; tm < 4; ++tm) {
                const int m = wm * 64 + tm * 16 + l16;
#pragma unroll
                for (int kh = 0; kh < 2; ++kh)
                    fa[tm][kh] = *reinterpret_cast<const bf16x8*>(
                        &Vs[m * 64 + (((kh * 4 + quad) ^ (m & 7)) * 8)]);
            }
#pragma unroll
            for (int tn = 0; tn < 4; ++tn) {
                const int n = wn * 64 + tn * 16 + l16;
#pragma unroll
                for (int kh = 0; kh < 2; ++kh)
                    fb[tn][kh] = *reinterpret_cast<const bf16x8*>(
                        &WVs[n * 64 + (((kh * 4 + quad) ^ (n & 7)) * 8)]);
            }
            __syncthreads();               // B: every wave done reading LDS
            if (kt < 7) stage_kv((kt + 1) * 64);   // overlap with V-MFMA
            // ---- V GEMM (stage(kt+1) in flight) ----
#pragma unroll
            for (int kh = 0; kh < 2; ++kh)
#pragma unroll
                for (int tm = 0; tm < 4; ++tm)
#pragma unroll
                    for (int tn = 0; tn < 4; ++tn)
                        accv[tm][tn] = __builtin_amdgcn_mfma_f32_16x16x32_bf16(
                            fa[tm][kh], fb[tn][kh], accv[tm][tn], 0, 0, 0);
        }

        // epilogue: write kv (bf16) and accumulate 32-row chunk partials
        float part[4][2];
#pragma unroll
        for (int tn = 0; tn < 4; ++tn) { part[tn][0] = 0.f; part[tn][1] = 0.f; }
#pragma unroll
        for (int tm = 0; tm < 4; ++tm) {
            const long row0 = arow0 + wm * 64 + tm * 16 + quad * 4;
#pragma unroll
            for (int tn = 0; tn < 4; ++tn) {
                const int col = (int)brow0 + wn * 64 + tn * 16 + l16;
                const float bkc = bwk[col];
                const float bvc = bwv[col];
#pragma unroll
                for (int r = 0; r < 4; ++r) {
                    const float kp = fmaxf(acck[tm][tn][r] + bkc, 0.f);
                    const float vp = accv[tm][tn][r] + bvc;
                    const __bf16 kb = (__bf16)(kp * vp);
                    kvb[(row0 + r) * D + col] = kb;
                    part[tn][tm >> 1] += (float)kb;
                }
            }
        }
        // reduce over quads (rows within the 32-row chunk) and store Csum
#pragma unroll
        for (int tn = 0; tn < 4; ++tn)
#pragma unroll
            for (int th = 0; th < 2; ++th) {
                float vv = part[tn][th];
                vv += __shfl_xor(vv, 16, 64);
                vv += __shfl_xor(vv, 32, 64);
                if (quad == 0) {
                    const int fc = ((int)(arow0 >> 5)) + wm * 2 + th; // flat chunk
                    const int bb = fc / NCH;
                    const int cc = fc - bb * NCH;
                    const int col = (int)brow0 + wn * 64 + tn * 16 + l16;
                    Csum[((long)bb * NCH + cc) * D + col] = vv;
                }
            }
    } else {
        // ============ q GEMM: 128x128 tile, LDS double-buffered ============
        __bf16* Asb[2] = { smem,         smem + 16384 };   // 128*64 each
        __bf16* Bsb[2] = { smem + 8192,  smem + 24576 };

        const int bidq = bid - 640;

        f32x4 acc[4][4];
#pragma unroll
        for (int i = 0; i < 4; ++i)
#pragma unroll
            for (int j = 0; j < 4; ++j)
                acc[i][j] = (f32x4){0.f, 0.f, 0.f, 0.f};

        const long arow0 = (long)(bidq & 127) * 128;   // mtile-inner
        const long brow0 = (long)(bidq >> 7) * 128;    // 4 ntile passes

        auto stage_q = [&](int kk, int p) {
#pragma unroll
            for (int j = 0; j < 4; ++j) {
                const int r0  = (j * 4 + wave) * 8;
                const int row = r0 + lrow;
                async16(&Asb[p][r0 * 64], &qn [(arow0 + row) * D + kk + lcs]);
                async16(&Bsb[p][r0 * 64], &wtq[(brow0 + row) * D + kk + lcs]);
            }
        };

        stage_q(0, 0);                     // prologue
        __syncthreads();                   // buf0 ready
        for (int kt = 0; kt < 8; ++kt) {
            const int p = kt & 1;
            if (kt < 7) stage_q((kt + 1) * 64, p ^ 1);   // into idle buffer

            bf16x8 af[4][2], bf[4][2];
#pragma unroll
            for (int tm = 0; tm < 4; ++tm) {
                const int m = wm * 64 + tm * 16 + l16;
#pragma unroll
                for (int kh = 0; kh < 2; ++kh)
                    af[tm][kh] = *reinterpret_cast<const bf16x8*>(
                        &Asb[p][m * 64 + (((kh * 4 + quad) ^ (m & 7)) * 8)]);
            }
#pragma unroll
            for (int tn = 0; tn < 4; ++tn) {
                const int n = wn * 64 + tn * 16 + l16;
#pragma unroll
                for (int kh = 0; kh < 2; ++kh)
                    bf[tn][kh] = *reinterpret_cast<const bf16x8*>(
                        &Bsb[p][n * 64 + (((kh * 4 + quad) ^ (n & 7)) * 8)]);
            }
#pragma unroll
            for (int kh = 0; kh < 2; ++kh)
#pragma unroll
                for (int tm = 0; tm < 4; ++tm)
#pragma unroll
                    for (int tn = 0; tn < 4; ++tn)
                        acc[tm][tn] = __builtin_amdgcn_mfma_f32_16x16x32_bf16(
                            af[tm][kh], bf[tn][kh], acc[tm][tn], 0, 0, 0);
            // barrier: (1) drains stage(kt+1) [covered by reads+MFMA above],
            // (2) all waves done reading buf p before kt+1 restages it.
            if (kt < 7) __syncthreads();
        }

#pragma unroll
        for (int tm = 0; tm < 4; ++tm) {
            const long row0 = arow0 + wm * 64 + tm * 16 + quad * 4;
#pragma unroll
            for (int tn = 0; tn < 4; ++tn) {
                const int col = (int)brow0 + wn * 64 + tn * 16 + l16;
                const float bv = bwq[col];
#pragma unroll
                for (int r = 0; r < 4; ++r)
                    qpb[(row0 + r) * D + col] =
                        (__bf16)fmaxf(acc[tm][tn][r] + bv, 0.f);
            }
        }
    }
}

// ---------------------------------------------------------------------------
// Kernel 3: sliding window (1024) via chunk-sum init + rolling edges,
// times relu(qp).  TI=32 query rows/block, 2 cols/thread.
// ---------------------------------------------------------------------------
__global__ __launch_bounds__(256) void window_kernel(
    const __bf16* __restrict__ kv, const float* __restrict__ Csum,
    const __bf16* __restrict__ qpb, float* __restrict__ out)
{
    const int iq   = blockIdx.x;        // 0..127
    const int b    = blockIdx.y;
    const int i0   = iq * TI;
    const int col2 = threadIdx.x * 2;

    const float* cs = Csum + (long)b * NCH * D + col2;
    float s0 = 0.f, s1 = 0.f;
#pragma unroll
    for (int c = 0; c < 32; ++c) {
        const float2 cv = *reinterpret_cast<const float2*>(cs + (long)(iq + c) * D);
        s0 += cv.x; s1 += cv.y;
    }

    const __bf16* kvb = kv  + (long)b * LKP * D + col2;
    const __bf16* qb  = qpb + (long)b * LQ  * D + col2;
    float*        ob  = out + (long)b * LQ  * D + col2;

#pragma unroll 8
    for (int i = i0; i < i0 + TI; ++i) {
        const bf16x2 qv = *reinterpret_cast<const bf16x2*>(qb + (long)i * D);
        *reinterpret_cast<float2*>(ob + (long)i * D) =
            make_float2((float)qv[0] * s0, (float)qv[1] * s1);
        const bf16x2 lead  = *reinterpret_cast<const bf16x2*>(kvb + (long)(i + CACHE) * D);
        const bf16x2 trail = *reinterpret_cast<const bf16x2*>(kvb + (long)i * D);
        s0 += (float)lead[0] - (float)trail[0];
        s1 += (float)lead[1] - (float)trail[1];
    }
}

// ---------------------------------------------------------------------------
extern "C" void kernel_launch(void* const* d_in, const int* in_sizes, int n_in,
                              void* d_out, int out_size, void* d_ws, size_t ws_size,
                              hipStream_t stream)
{
    const float* q   = (const float*)d_in[0];
    const float* k   = (const float*)d_in[1];
    const float* v   = (const float*)d_in[2];
    const float* gq  = (const float*)d_in[3];
    const float* bq  = (const float*)d_in[4];
    const float* gk  = (const float*)d_in[5];
    const float* bk  = (const float*)d_in[6];
    const float* gv  = (const float*)d_in[7];
    const float* bv  = (const float*)d_in[8];
    const float* Wq  = (const float*)d_in[9];
    const float* bwq = (const float*)d_in[10];
    const float* Wk  = (const float*)d_in[11];
    const float* bwk = (const float*)d_in[12];
    const float* Wv  = (const float*)d_in[13];
    const float* bwv = (const float*)d_in[14];
    float* out = (float*)d_out;

    // Workspace layout (k/v-side tensors per-batch padded: stride LKP rows)
    char* ws = (char*)d_ws;
    __bf16* qn   = (__bf16*)ws;                      // [MQ ][D] bf16
    __bf16* kn   = qn  + (long)MQ  * D;              // [MKP][D] bf16 (padded)
    __bf16* vn   = kn  + (long)MKP * D;              // [MKP][D] bf16 (padded)
    __bf16* qpb  = vn  + (long)MKP * D;              // [MQ ][D] bf16  relu(qp)
    __bf16* kvb  = qpb + (long)MQ  * D;              // [MKP][D] bf16 (padded)
    __bf16* wtq  = kvb + (long)MKP * D;              // [D][D] bf16 transposed
    __bf16* wtk  = wtq + (long)D * D;
    __bf16* wtv  = wtk + (long)D * D;
    float*  Csum = (float*)(wtv + (long)D * D);      // [B][NCH][D] f32

    // 1) LN(q,k,v) + weight transpose in ONE dispatch
    //    (1 row per wave, 4 rows/block: z=0 uses 4096 blocks, z=1/2 use 5120)
    prep_kernel<<<dim3(5120, 4), 256, 0, stream>>>(
        q, k, v, gq, bq, gk, bk, gv, bv, Wq, Wk, Wv,
        qn, kn, vn, wtq, wtk, wtv);

    // 2) kv-dual-GEMM (640 blocks, FIRST: LPT) + qp-GEMM (512 blocks)
    gemm_fused_kernel<<<640 + 512, 256, 0, stream>>>(
        qn, kn, vn, wtq, wtk, wtv, bwq, bwk, bwv, qpb, kvb, Csum);

    // 3) window sum x relu(qp)
    window_kernel<<<dim3(LQ / TI, B), 256, 0, stream>>>(kvb, Csum, qpb, out);
}

// Round 18
// 225.921 us; speedup vs baseline: 1.0200x; 1.0080x over previous
//
#include <hip/hip_runtime.h>

// Problem constants
#define B     4
#define LQ    4096
#define LK    5119
#define LKP   5120              // per-batch padded rows (160 chunks of 32)
#define D     512
#define CACHE 1024
#define MQ    (B * LQ)          // 16384 = 128*128
#define MKP   (B * LKP)         // 20480 = 160*128
#define NCH   160               // 32-row chunks per batch
#define TI    32                // query rows per window block

typedef float  f32x4  __attribute__((ext_vector_type(4)));
typedef __bf16 bf16x2 __attribute__((ext_vector_type(2)));
typedef __bf16 bf16x4 __attribute__((ext_vector_type(4)));
typedef __bf16 bf16x8 __attribute__((ext_vector_type(8)));

// async global->LDS, 16B per lane; lds base wave-uniform (HW adds lane*16)
__device__ __forceinline__ void async16(void* lds, const void* g)
{
    __builtin_amdgcn_global_load_lds(
        (__attribute__((address_space(1))) void*)(g),
        (__attribute__((address_space(3))) void*)(lds),
        16, 0, 0);
}

// ---------------------------------------------------------------------------
// Kernel 1 (prep): z in {0,1,2}: LayerNorm -> bf16.
// R10 (verified): ONE WAVE PER ROW, instruction-contiguous loads/stores —
// lane i loads row[i*4] and row[256+i*4] (two dwordx4, each a contiguous
// 1KB wave footprint).  Fixed the 2.1-2.4 TB/s wall of the 64B-chunk
// layouts (R2/R3/R6) whose per-instruction lane stride wasted 3/4 of each
// cacheline fetch.  z == 3: weight transpose f32->bf16 (unchanged).
// NOTE (R7 lesson): plain stores only — nt-stores bypass L3 and force the
// consumer GEMM to re-read everything from HBM.
// ---------------------------------------------------------------------------
__global__ __launch_bounds__(256) void prep_kernel(
    const float* __restrict__ q, const float* __restrict__ k,
    const float* __restrict__ v,
    const float* __restrict__ gq, const float* __restrict__ bq,
    const float* __restrict__ gk, const float* __restrict__ bk,
    const float* __restrict__ gv, const float* __restrict__ bv,
    const float* __restrict__ Wq, const float* __restrict__ Wk,
    const float* __restrict__ Wv,
    __bf16* __restrict__ qn, __bf16* __restrict__ kn, __bf16* __restrict__ vn,
    __bf16* __restrict__ wtq, __bf16* __restrict__ wtk, __bf16* __restrict__ wtv)
{
    const int z = blockIdx.y;

    if (z == 3) {               // ---- weight transpose-convert ----
        const int idx = blockIdx.x;
        if (idx >= 384) return;
        const int zz  = idx >> 7;        // 0..2
        const int rem = idx & 127;
        const float* W = (zz == 0) ? Wq : (zz == 1) ? Wk : Wv;
        __bf16*     Wt = (zz == 0) ? wtq : (zz == 1) ? wtk : wtv;
        const int n  = (rem & 1) * 256 + threadIdx.x;
        const int k0 = (rem >> 1) * 8;
        bf16x8 o;
#pragma unroll
        for (int j = 0; j < 8; ++j)
            o[j] = (__bf16)W[(long)(k0 + j) * D + n];
        *reinterpret_cast<bf16x8*>(Wt + (long)n * D + k0) = o;
        return;
    }

    // ---- LayerNorm: one wave per row, instruction-contiguous ----
    const float *x, *g, *bb; __bf16* o;
    if (z == 0)      { x = q; g = gq; bb = bq; o = qn; }
    else if (z == 1) { x = k; g = gk; bb = bk; o = kn; }
    else             { x = v; g = gv; bb = bv; o = vn; }

    const int nrows = (z == 0) ? MQ : MKP;
    const int wid   = threadIdx.x >> 6;          // 0..3: wave in block
    const int lane  = threadIdx.x & 63;
    const int rp    = blockIdx.x * 4 + wid;      // padded row id
    if (rp >= nrows) return;                     // z==0 tail blocks

    long rin; bool valid = true;
    if (z == 0) rin = rp;
    else {
        const int bch = rp / LKP;
        int i = rp - bch * LKP;
        if (i == LK) { valid = false; i = LK - 1; }  // pad row: dummy load
        rin = (long)bch * LK + i;
    }

    const int    c0 = lane * 4;                  // 16B chunk within half-row
    const float* xr = x + rin * D;

    // two loads, each a contiguous 1KB wave footprint
    const float4 a0 = *reinterpret_cast<const float4*>(xr + c0);
    const float4 a1 = *reinterpret_cast<const float4*>(xr + 256 + c0);

    float s  = a0.x + a0.y + a0.z + a0.w + a1.x + a1.y + a1.z + a1.w;
    float ss = a0.x*a0.x + a0.y*a0.y + a0.z*a0.z + a0.w*a0.w
             + a1.x*a1.x + a1.y*a1.y + a1.z*a1.z + a1.w*a1.w;
#pragma unroll
    for (int m = 1; m <= 32; m <<= 1) {          // full 64-lane butterfly
        s  += __shfl_xor(s,  m, 64);
        ss += __shfl_xor(ss, m, 64);
    }
    const float mean = s * (1.f / (float)D);
    const float var  = ss * (1.f / (float)D) - mean * mean;
    const float rs   = rsqrtf(var + 1e-5f);

    const float4 g0 = *reinterpret_cast<const float4*>(g  + c0);
    const float4 g1 = *reinterpret_cast<const float4*>(g  + 256 + c0);
    const float4 b0 = *reinterpret_cast<const float4*>(bb + c0);
    const float4 b1 = *reinterpret_cast<const float4*>(bb + 256 + c0);

    bf16x4 o0, o1;
    o0[0] = (__bf16)((a0.x - mean) * rs * g0.x + b0.x);
    o0[1] = (__bf16)((a0.y - mean) * rs * g0.y + b0.y);
    o0[2] = (__bf16)((a0.z - mean) * rs * g0.z + b0.z);
    o0[3] = (__bf16)((a0.w - mean) * rs * g0.w + b0.w);
    o1[0] = (__bf16)((a1.x - mean) * rs * g1.x + b1.x);
    o1[1] = (__bf16)((a1.y - mean) * rs * g1.y + b1.y);
    o1[2] = (__bf16)((a1.z - mean) * rs * g1.z + b1.z);
    o1[3] = (__bf16)((a1.w - mean) * rs * g1.w + b1.w);

    if (valid) {
        __bf16* orow = o + (long)rp * D;
        *reinterpret_cast<bf16x4*>(orow + c0)       = o0;   // contiguous 512B
        *reinterpret_cast<bf16x4*>(orow + 256 + c0) = o1;   // contiguous 512B
    }
}

// ---------------------------------------------------------------------------
// Kernel 2 (gemm_fused):
//   bid <  640 -> kv = relu(kn@Wk + bwk) * (vn@Wv + bwv) (128x128 tile) with
//                 fused 32-row chunk sums stored to Csum.
//   bid >= 640 -> qp = relu(qn@Wq + bwq) (128x128 tile).
// R2a (LPT): kv blocks (the ~2x-longer jobs) launch FIRST.
// R11: kv dual-GEMM split into TWO SEQUENTIAL PASSES (K-pass then V-pass),
// each an instance of the SAME one-barrier-per-step LDS double-buffered
// 128x128 GEMM used by the q path since R3 (verified).
// R15 fix: NO pointer arrays to __shared__ inside the lambda (hipcc emits
// "unsupported static initializer: addrspacecast" for them on gfx950) —
// buffer bases computed as smem + p*16384 instead.
// Pass transition is barrier-free: pass2's stage(0,buf0) is disjoint from
// pass1's kt=7 reads (buf1).  acck/accv both live in registers; epilogue
// (relu(k)*v + chunk sums) unchanged.
// Block order: mtile-INNER on both paths (XCD affinity: offsets ≡0 mod 8).
// BK=64, async16 staging, XOR-swizzled 16B chunks (conflict-free).
// ---------------------------------------------------------------------------
__global__ __launch_bounds__(256, 2) void gemm_fused_kernel(
    const __bf16* __restrict__ qn, const __bf16* __restrict__ kn,
    const __bf16* __restrict__ vn,
    const __bf16* __restrict__ wtq, const __bf16* __restrict__ wtk,
    const __bf16* __restrict__ wtv,
    const float* __restrict__ bwq, const float* __restrict__ bwk,
    const float* __restrict__ bwv,
    __bf16* __restrict__ qpb, __bf16* __restrict__ kvb,
    float* __restrict__ Csum)
{
    __shared__ __attribute__((aligned(16))) __bf16 smem[32768];  // 64 KB

    const int bid  = blockIdx.x;
    const int tid  = threadIdx.x;
    const int lane = tid & 63;
    const int wave = tid >> 6;
    const int quad = lane >> 4;
    const int l16  = lane & 15;
    const int wm   = wave >> 1;
    const int wn   = wave & 1;
    const int lrow = lane >> 3;                    // 0..7
    const int lcs  = ((lane & 7) ^ lrow) * 8;      // swizzled k-col (bf16)

    // One-barrier-per-step double-buffered 128x128 GEMM over K=512 (8 steps
    // of BK=64).  Buffer parity p: A at smem+p*16384, B at smem+8192+p*16384.
    // acc += A[arow0..+128) x Bt[brow0..+128)^T.
    auto gemm128 = [&](const __bf16* __restrict__ A,
                       const __bf16* __restrict__ Bt,
                       f32x4 (&acc)[4][4], long arow0, long brow0) {
        auto stg = [&](int kk, int p) {
            __bf16* As = smem + p * 16384;
            __bf16* Bs = smem + 8192 + p * 16384;
#pragma unroll
            for (int j = 0; j < 4; ++j) {
                const int r0  = (j * 4 + wave) * 8;
                const int row = r0 + lrow;
                async16(&As[r0 * 64], &A [(arow0 + row) * D + kk + lcs]);
                async16(&Bs[r0 * 64], &Bt[(brow0 + row) * D + kk + lcs]);
            }
        };
        stg(0, 0);                     // prologue
        __syncthreads();               // buf0 staged (implicit vmcnt drain)
        for (int kt = 0; kt < 8; ++kt) {
            const int p = kt & 1;
            if (kt < 7) stg((kt + 1) * 64, p ^ 1);   // into idle buffer

            const __bf16* As = smem + p * 16384;
            const __bf16* Bs = smem + 8192 + p * 16384;
            bf16x8 af[4][2], bf[4][2];
#pragma unroll
            for (int tm = 0; tm < 4; ++tm) {
                const int m = wm * 64 + tm * 16 + l16;
#pragma unroll
                for (int kh = 0; kh < 2; ++kh)
                    af[tm][kh] = *reinterpret_cast<const bf16x8*>(
                        &As[m * 64 + (((kh * 4 + quad) ^ (m & 7)) * 8)]);
            }
#pragma unroll
            for (int tn = 0; tn < 4; ++tn) {
                const int n = wn * 64 + tn * 16 + l16;
#pragma unroll
                for (int kh = 0; kh < 2; ++kh)
                    bf[tn][kh] = *reinterpret_cast<const bf16x8*>(
                        &Bs[n * 64 + (((kh * 4 + quad) ^ (n & 7)) * 8)]);
            }
#pragma unroll
            for (int kh = 0; kh < 2; ++kh)
#pragma unroll
                for (int tm = 0; tm < 4; ++tm)
#pragma unroll
                    for (int tn = 0; tn < 4; ++tn)
                        acc[tm][tn] = __builtin_amdgcn_mfma_f32_16x16x32_bf16(
                            af[tm][kh], bf[tn][kh], acc[tm][tn], 0, 0, 0);
            // barrier: (1) drains stage(kt+1) [covered by reads+MFMA above],
            // (2) all waves done reading buf p before kt+1 restages it.
            if (kt < 7) __syncthreads();
        }
    };

    if (bid < 640) {
        // ================= kv: two sequential 128x128 GEMMs =================
        const int ntile = bid / 160;      // 0..3 (mtile-inner, 160%8==0)
        const int mtile = bid - ntile * 160;
        const long arow0 = (long)mtile * 128;
        const long brow0 = (long)ntile * 128;

        f32x4 acck[4][4];
#pragma unroll
        for (int i = 0; i < 4; ++i)
#pragma unroll
            for (int j = 0; j < 4; ++j)
                acck[i][j] = (f32x4){0.f, 0.f, 0.f, 0.f};
        gemm128(kn, wtk, acck, arow0, brow0);     // K-pass

        f32x4 accv[4][4];
#pragma unroll
        for (int i = 0; i < 4; ++i)
#pragma unroll
            for (int j = 0; j < 4; ++j)
                accv[i][j] = (f32x4){0.f, 0.f, 0.f, 0.f};
        gemm128(vn, wtv, accv, arow0, brow0);     // V-pass

        // epilogue: write kv (bf16) and accumulate 32-row chunk partials
        float part[4][2];
#pragma unroll
        for (int tn = 0; tn < 4; ++tn) { part[tn][0] = 0.f; part[tn][1] = 0.f; }
#pragma unroll
        for (int tm = 0; tm < 4; ++tm) {
            const long row0 = arow0 + wm * 64 + tm * 16 + quad * 4;
#pragma unroll
            for (int tn = 0; tn < 4; ++tn) {
                const int col = (int)brow0 + wn * 64 + tn * 16 + l16;
                const float bkc = bwk[col];
                const float bvc = bwv[col];
#pragma unroll
                for (int r = 0; r < 4; ++r) {
                    const float kp = fmaxf(acck[tm][tn][r] + bkc, 0.f);
                    const float vp = accv[tm][tn][r] + bvc;
                    const __bf16 kb = (__bf16)(kp * vp);
                    kvb[(row0 + r) * D + col] = kb;
                    part[tn][tm >> 1] += (float)kb;
                }
            }
        }
        // reduce over quads (rows within the 32-row chunk) and store Csum
#pragma unroll
        for (int tn = 0; tn < 4; ++tn)
#pragma unroll
            for (int th = 0; th < 2; ++th) {
                float vv = part[tn][th];
                vv += __shfl_xor(vv, 16, 64);
                vv += __shfl_xor(vv, 32, 64);
                if (quad == 0) {
                    const int fc = ((int)(arow0 >> 5)) + wm * 2 + th; // flat chunk
                    const int bb = fc / NCH;
                    const int cc = fc - bb * NCH;
                    const int col = (int)brow0 + wn * 64 + tn * 16 + l16;
                    Csum[((long)bb * NCH + cc) * D + col] = vv;
                }
            }
    } else {
        // ================= q GEMM: 128x128 tile =================
        const int bidq = bid - 640;
        const long arow0 = (long)(bidq & 127) * 128;   // mtile-inner
        const long brow0 = (long)(bidq >> 7) * 128;    // 4 ntile passes

        f32x4 acc[4][4];
#pragma unroll
        for (int i = 0; i < 4; ++i)
#pragma unroll
            for (int j = 0; j < 4; ++j)
                acc[i][j] = (f32x4){0.f, 0.f, 0.f, 0.f};
        gemm128(qn, wtq, acc, arow0, brow0);

#pragma unroll
        for (int tm = 0; tm < 4; ++tm) {
            const long row0 = arow0 + wm * 64 + tm * 16 + quad * 4;
#pragma unroll
            for (int tn = 0; tn < 4; ++tn) {
                const int col = (int)brow0 + wn * 64 + tn * 16 + l16;
                const float bv = bwq[col];
#pragma unroll
                for (int r = 0; r < 4; ++r)
                    qpb[(row0 + r) * D + col] =
                        (__bf16)fmaxf(acc[tm][tn][r] + bv, 0.f);
            }
        }
    }
}

// ---------------------------------------------------------------------------
// Kernel 3: sliding window (1024) via chunk-sum init + rolling edges,
// times relu(qp).  TI=32 query rows/block, 2 cols/thread.
// ---------------------------------------------------------------------------
__global__ __launch_bounds__(256) void window_kernel(
    const __bf16* __restrict__ kv, const float* __restrict__ Csum,
    const __bf16* __restrict__ qpb, float* __restrict__ out)
{
    const int iq   = blockIdx.x;        // 0..127
    const int b    = blockIdx.y;
    const int i0   = iq * TI;
    const int col2 = threadIdx.x * 2;

    const float* cs = Csum + (long)b * NCH * D + col2;
    float s0 = 0.f, s1 = 0.f;
#pragma unroll
    for (int c = 0; c < 32; ++c) {
        const float2 cv = *reinterpret_cast<const float2*>(cs + (long)(iq + c) * D);
        s0 += cv.x; s1 += cv.y;
    }

    const __bf16* kvb = kv  + (long)b * LKP * D + col2;
    const __bf16* qb  = qpb + (long)b * LQ  * D + col2;
    float*        ob  = out + (long)b * LQ  * D + col2;

#pragma unroll 8
    for (int i = i0; i < i0 + TI; ++i) {
        const bf16x2 qv = *reinterpret_cast<const bf16x2*>(qb + (long)i * D);
        *reinterpret_cast<float2*>(ob + (long)i * D) =
            make_float2((float)qv[0] * s0, (float)qv[1] * s1);
        const bf16x2 lead  = *reinterpret_cast<const bf16x2*>(kvb + (long)(i + CACHE) * D);
        const bf16x2 trail = *reinterpret_cast<const bf16x2*>(kvb + (long)i * D);
        s0 += (float)lead[0] - (float)trail[0];
        s1 += (float)lead[1] - (float)trail[1];
    }
}

// ---------------------------------------------------------------------------
extern "C" void kernel_launch(void* const* d_in, const int* in_sizes, int n_in,
                              void* d_out, int out_size, void* d_ws, size_t ws_size,
                              hipStream_t stream)
{
    const float* q   = (const float*)d_in[0];
    const float* k   = (const float*)d_in[1];
    const float* v   = (const float*)d_in[2];
    const float* gq  = (const float*)d_in[3];
    const float* bq  = (const float*)d_in[4];
    const float* gk  = (const float*)d_in[5];
    const float* bk  = (const float*)d_in[6];
    const float* gv  = (const float*)d_in[7];
    const float* bv  = (const float*)d_in[8];
    const float* Wq  = (const float*)d_in[9];
    const float* bwq = (const float*)d_in[10];
    const float* Wk  = (const float*)d_in[11];
    const float* bwk = (const float*)d_in[12];
    const float* Wv  = (const float*)d_in[13];
    const float* bwv = (const float*)d_in[14];
    float* out = (float*)d_out;

    // Workspace layout (k/v-side tensors per-batch padded: stride LKP rows)
    char* ws = (char*)d_ws;
    __bf16* qn   = (__bf16*)ws;                      // [MQ ][D] bf16
    __bf16* kn   = qn  + (long)MQ  * D;              // [MKP][D] bf16 (padded)
    __bf16* vn   = kn  + (long)MKP * D;              // [MKP][D] bf16 (padded)
    __bf16* qpb  = vn  + (long)MKP * D;              // [MQ ][D] bf16  relu(qp)
    __bf16* kvb  = qpb + (long)MQ  * D;              // [MKP][D] bf16 (padded)
    __bf16* wtq  = kvb + (long)MKP * D;              // [D][D] bf16 transposed
    __bf16* wtk  = wtq + (long)D * D;
    __bf16* wtv  = wtk + (long)D * D;
    float*  Csum = (float*)(wtv + (long)D * D);      // [B][NCH][D] f32

    // 1) LN(q,k,v) + weight transpose in ONE dispatch
    //    (1 row per wave, 4 rows/block: z=0 uses 4096 blocks, z=1/2 use 5120)
    prep_kernel<<<dim3(5120, 4), 256, 0, stream>>>(
        q, k, v, gq, bq, gk, bk, gv, bv, Wq, Wk, Wv,
        qn, kn, vn, wtq, wtk, wtv);

    // 2) kv-dual-GEMM (640 blocks, FIRST: LPT) + qp-GEMM (512 blocks)
    gemm_fused_kernel<<<640 + 512, 256, 0, stream>>>(
        qn, kn, vn, wtq, wtk, wtv, bwq, bwk, bwv, qpb, kvb, Csum);

    // 3) window sum x relu(qp)
    window_kernel<<<dim3(LQ / TI, B), 256, 0, stream>>>(kvb, Csum, qpb, out);
}